// Round 12
// baseline (151.404 us; speedup 1.0000x reference)
//
#include <hip/hip_runtime.h>
#include <hip/hip_bf16.h>

// Problem constants (B=1)
#define T_DIM 4096
#define E_DIM 1024
#define H_DIM 16
#define HD_DIM 64
#define LOG2E_F 1.4426950408889634f
#define QSCALE_F (0.125f * LOG2E_F)   // SCALE * log2(e), folded into Qp

typedef __bf16 bf16_t;
typedef __bf16 bf16x8 __attribute__((ext_vector_type(8)));
typedef __bf16 bf16x4 __attribute__((ext_vector_type(4)));
typedef float  f32x4  __attribute__((ext_vector_type(4)));

// ---- helpers ----
__device__ inline void stage8(bf16_t* dst, const float* src) {
  const f32x4* s4 = (const f32x4*)src;
  f32x4 a = s4[0], b = s4[1];
  bf16x8 o;
  o[0] = (bf16_t)a[0]; o[1] = (bf16_t)a[1]; o[2] = (bf16_t)a[2]; o[3] = (bf16_t)a[3];
  o[4] = (bf16_t)b[0]; o[5] = (bf16_t)b[1]; o[6] = (bf16_t)b[2]; o[7] = (bf16_t)b[3];
  *(bf16x8*)dst = o;
}
__device__ inline void stage8(bf16_t* dst, const bf16_t* src) {
  *(bf16x8*)dst = *(const bf16x8*)src;
}

__device__ inline void gld_lds16(const bf16_t* g, bf16_t* l) {
  __builtin_amdgcn_global_load_lds(
      (const __attribute__((address_space(1))) unsigned int*)g,
      (__attribute__((address_space(3))) unsigned int*)l, 16, 0, 0);
}

__device__ inline float fexp2(float x) {  // raw v_exp_f32 (exp2)
  float r;
  asm("v_exp_f32 %0, %1" : "=v"(r) : "v"(x));
  return r;
}

// raw barrier (no implicit vmcnt(0) drain) + compiler memory fence
__device__ inline void block_sync() {
  asm volatile("" ::: "memory");
  __builtin_amdgcn_s_barrier();
  asm volatile("" ::: "memory");
}

// ---- fp32 -> bf16 conversion for all 7 inputs (one launch) ----
__global__ __launch_bounds__(256) void cvt_all(
    const float* __restrict__ q, const float* __restrict__ k, const float* __restrict__ v,
    const float* __restrict__ Wq, const float* __restrict__ Wk,
    const float* __restrict__ Wv, const float* __restrict__ Wo,
    bf16_t* qb, bf16_t* kb, bf16_t* vb,
    bf16_t* Wqb, bf16_t* Wkb, bf16_t* Wvb, bf16_t* Wob) {
  for (int u = blockIdx.x * 256 + threadIdx.x; u < 2097152; u += gridDim.x * 256) {
    const float* s; bf16_t* d; int i;
    if (u < 1572864) {
      int seg = u >> 19, off = u & 524287;
      s = seg == 0 ? q : (seg == 1 ? k : v);
      d = seg == 0 ? qb : (seg == 1 ? kb : vb);
      i = off;
    } else {
      int w = u - 1572864;
      int seg = w >> 17, off = w & 131071;
      s = seg == 0 ? Wq : seg == 1 ? Wk : seg == 2 ? Wv : Wo;
      d = seg == 0 ? Wqb : seg == 1 ? Wkb : seg == 2 ? Wvb : Wob;
      i = off;
    }
    stage8(d + (size_t)i * 8, s + (size_t)i * 8);
  }
}

// ---- bf16 GEMM tile body (m97 structure): C = (A[M][1024] x B[N][1024]^T)*cs
template <int MF, int NF, typename TC>
__device__ __forceinline__ void gemm_body(const bf16_t* __restrict__ A,
                                          const bf16_t* __restrict__ B,
                                          TC* __restrict__ C,
                                          int ldC, int bm, int bn, float cs) {
  constexpr int BM = 32 * MF, BN = 32 * NF;
  __shared__ alignas(16) bf16_t As[BM][64];
  __shared__ alignas(16) bf16_t Bs[BN][64];
  const int tid  = threadIdx.x;
  const int lane = tid & 63, w = tid >> 6;
  const int g = lane >> 4, l15 = lane & 15;
  const int wr = w >> 1, wc = w & 1;

  f32x4 acc[MF][NF] = {};

  for (int kt = 0; kt < 1024; kt += 64) {
    if (kt) __syncthreads();
#pragma unroll
    for (int p = 0; p < MF; ++p) {
      int s = p * 256 + tid;
      int row = s >> 3, c = s & 7;
      int cg = c ^ (row & 7);
      gld_lds16(&A[(size_t)(bm + row) * 1024 + kt + cg * 8], &As[0][0] + s * 8);
    }
#pragma unroll
    for (int p = 0; p < NF; ++p) {
      int s = p * 256 + tid;
      int row = s >> 3, c = s & 7;
      int cg = c ^ (row & 7);
      gld_lds16(&B[(size_t)(bn + row) * 1024 + kt + cg * 8], &Bs[0][0] + s * 8);
    }
    asm volatile("s_waitcnt vmcnt(0)" ::: "memory");
    __syncthreads();

#pragma unroll
    for (int hh = 0; hh < 2; ++hh) {
      bf16x8 af[MF], bfr[NF];
#pragma unroll
      for (int m = 0; m < MF; ++m) {
        int row = wr * (16 * MF) + m * 16 + l15;
        af[m] = *(const bf16x8*)(&As[0][0] + row * 64 + (((hh * 4 + g) ^ (row & 7)) * 8));
      }
#pragma unroll
      for (int n = 0; n < NF; ++n) {
        int row = wc * (16 * NF) + n * 16 + l15;
        bfr[n] = *(const bf16x8*)(&Bs[0][0] + row * 64 + (((hh * 4 + g) ^ (row & 7)) * 8));
      }
#pragma unroll
      for (int m = 0; m < MF; ++m)
#pragma unroll
        for (int n = 0; n < NF; ++n)
          acc[m][n] = __builtin_amdgcn_mfma_f32_16x16x32_bf16(af[m], bfr[n], acc[m][n], 0, 0, 0);
    }
  }

#pragma unroll
  for (int m = 0; m < MF; ++m)
#pragma unroll
    for (int n = 0; n < NF; ++n)
#pragma unroll
      for (int r = 0; r < 4; ++r) {
        int row = bm + wr * (16 * MF) + m * 16 + g * 4 + r;
        int col = bn + wc * (16 * NF) + n * 16 + l15;
        C[(size_t)row * ldC + col] = (TC)(acc[m][n][r] * cs);
      }
}

// ---- fused Q/K/V projections: one launch, 768 blocks (3 blocks/CU) ----
__global__ __launch_bounds__(256) void proj_qkv(
    const bf16_t* __restrict__ qb, const bf16_t* __restrict__ kb,
    const bf16_t* __restrict__ vb,
    const bf16_t* __restrict__ Wqb, const bf16_t* __restrict__ Wkb,
    const bf16_t* __restrict__ Wvb,
    bf16_t* Qp, bf16_t* Kp, bf16_t* Vt) {
  const int bid = blockIdx.x;
  const int which = bid >> 8, t = bid & 255;
  const bf16_t *A, *B; bf16_t* C; int ldC, bm, bn; float cs;
  if (which == 0) {
    A = qb;  B = Wqb; C = Qp; ldC = 1024;
    bm = (t >> 3) * 128; bn = (t & 7) * 128; cs = QSCALE_F;
  } else if (which == 1) {
    A = kb;  B = Wkb; C = Kp; ldC = 1024;
    bm = (t >> 3) * 128; bn = (t & 7) * 128; cs = 1.0f;
  } else {
    A = Wvb; B = vb;  C = Vt; ldC = 4096;
    bm = (t >> 5) * 128; bn = (t & 31) * 128; cs = 1.0f;
  }
  gemm_body<4, 4, bf16_t>(A, B, C, ldC, bm, bn, cs);
}

// ---- final GEMM: out = Oa @ Wo^T, 64x128 tiles (grid 8x64, 2 blocks/CU) ----
__global__ __launch_bounds__(256) void gemm_fin(const bf16_t* __restrict__ A,
                                                const bf16_t* __restrict__ B,
                                                float* __restrict__ C) {
  gemm_body<2, 4, float>(A, B, C, 1024, blockIdx.y * 64, blockIdx.x * 128, 1.0f);
}

// ---- fallback GEMM (fp32 staging, used only if ws too small) ----
template <typename TA, typename TB, typename TC>
__global__ __launch_bounds__(256) void gemm_bt(const TA* __restrict__ A,
                                               const TB* __restrict__ B,
                                               TC* __restrict__ C,
                                               int M, int N, int K, float cscale) {
  __shared__ alignas(16) bf16_t As[128][40];
  __shared__ alignas(16) bf16_t Bs[128][40];
  const int tid  = threadIdx.x;
  const int lane = tid & 63, w = tid >> 6;
  const int g = lane >> 4, l15 = lane & 15;
  const int wr = w >> 1, wc = w & 1;
  const int bm = blockIdx.y * 128, bn = blockIdx.x * 128;

  f32x4 acc[4][4] = {};

  for (int kt = 0; kt < K; kt += 32) {
    __syncthreads();
#pragma unroll
    for (int i = 0; i < 2; ++i) {
      int vv  = tid + i * 256;
      int row = vv >> 2, c8 = (vv & 3) * 8;
      stage8(&As[row][c8], &A[(size_t)(bm + row) * K + kt + c8]);
      stage8(&Bs[row][c8], &B[(size_t)(bn + row) * K + kt + c8]);
    }
    __syncthreads();

    bf16x8 af[4], bfr[4];
#pragma unroll
    for (int m = 0; m < 4; ++m)
      af[m] = *(const bf16x8*)&As[wr * 64 + m * 16 + l15][g * 8];
#pragma unroll
    for (int n = 0; n < 4; ++n)
      bfr[n] = *(const bf16x8*)&Bs[wc * 64 + n * 16 + l15][g * 8];
#pragma unroll
    for (int m = 0; m < 4; ++m)
#pragma unroll
      for (int n = 0; n < 4; ++n)
        acc[m][n] = __builtin_amdgcn_mfma_f32_16x16x32_bf16(af[m], bfr[n], acc[m][n], 0, 0, 0);
  }

#pragma unroll
  for (int m = 0; m < 4; ++m)
#pragma unroll
    for (int n = 0; n < 4; ++n)
#pragma unroll
      for (int r = 0; r < 4; ++r) {
        int row = bm + wr * 64 + m * 16 + g * 4 + r;
        int col = bn + wc * 64 + n * 16 + l15;
        C[(size_t)row * N + col] = (TC)(acc[m][n][r] * cscale);
      }
}

// ---- Flash attention, causal, online softmax (log2 domain, pre-scaled Q) ----
// KVBLK=32, QBLK=64, 4 waves (256 thr), 1024 blocks big-first.
// LDS = 24.5 KB -> 6 blocks/CU (24 waves): TLP is the lever (round-11 counters:
// 54% combined pipe util at 24.8% occupancy).
// Schedule identical to round 11, scaled: delayed PV, K double-/V triple-
// buffered, one barrier per phase, 1-ahead issue, chunk-XOR swizzles.
// Swapped-operand QK^T: lane l holds q = qrow+l15, k-band {16*j16+4g+r};
// m/l row-reduced across the g-quad only in the rescale branch; l kept as
// per-lane partial, one quad-reduce in the epilogue.
__global__ __launch_bounds__(256) void attn_fwd(const bf16_t* __restrict__ Qp,
                                                const bf16_t* __restrict__ Kp,
                                                const bf16_t* __restrict__ Vt,
                                                bf16_t* __restrict__ Oattn) {
  const int bid = blockIdx.x;
  const int h  = bid & 15;             // xcd = bid%8 = h%8: 2 heads per XCD L2
  const int qi = 63 - (bid >> 4);      // 0..63, big blocks dispatched first
  const int tid = threadIdx.x, lane = tid & 63, w = tid >> 6;
  const int g = lane >> 4, l15 = lane & 15;
  const int qrow = qi * 64 + w * 16;

  __shared__ alignas(16) bf16_t Ks[2][32][64];   // 4 KB/tile: rows k, cols d
  __shared__ alignas(16) bf16_t Vs[3][64][32];   // 4 KB/tile: rows d, cols k
  __shared__ alignas(16) bf16_t Plds[4][16][32]; // 1 KB/wave: rows q, cols k

  bf16x8 qf[2];
  {
    const bf16_t* qp = &Qp[(size_t)(qrow + l15) * E_DIM + h * 64 + g * 8];
    qf[0] = *(const bf16x8*)qp;
    qf[1] = *(const bf16x8*)(qp + 32);
  }

  // staging: one gld_lds16 per thread per K and per V tile (4 KB = 256x16B)
  const int krow = tid >> 3;                       // 0..31
  const int kcg  = ((tid & 7) ^ (krow & 7)) * 8;   // source-side chunk XOR
  const bf16_t* srcK = Kp + (size_t)krow * E_DIM + h * 64 + kcg;
  const int vrow = tid >> 2;                       // 0..63
  const int vcg  = ((tid & 3) ^ (vrow & 3)) * 8;
  const bf16_t* srcV = Vt + (size_t)(h * 64 + vrow) * T_DIM + vcg;
  bf16_t* KsAll = &Ks[0][0][0];
  bf16_t* VsAll = &Vs[0][0][0];
  const size_t KADV = (size_t)32 * E_DIM;
  const int nt = 2 * qi + 2;

  auto issue = [&](int t) {
    gld_lds16(srcK + (size_t)t * KADV, KsAll + (t & 1) * 2048 + tid * 8);
    gld_lds16(srcV + (size_t)t * 32,   VsAll + (t % 3) * 2048 + tid * 8);
  };

  f32x4 acc[4] = {};          // acc[c][r]: O^T[d = c*16 + g*4 + r][q = l15]
  float m_s = -1e30f, l_p = 0.f;   // m row-uniform; l per-lane partial

  const int psw = (g ^ (l15 & 3)) << 4;   // P/V chunk-XOR byte offset
  auto pv = [&](int t) {
    const char* Vb = (const char*)(VsAll + (t % 3) * 2048);
    bf16x8 pf0 = *(const bf16x8*)((const char*)&Plds[w][l15][0] + psw);
#pragma unroll
    for (int c = 0; c < 4; ++c) {
      const int vr = c * 16 + l15;
      bf16x8 v0 = *(const bf16x8*)(Vb + vr * 64 + psw);   // vr&3 == l15&3
      acc[c] = __builtin_amdgcn_mfma_f32_16x16x32_bf16(v0, pf0, acc[c], 0, 0, 0);
    }
  };

  issue(0);

  for (int j = 0; j < nt; ++j) {
    asm volatile("s_waitcnt vmcnt(0)" ::: "memory");
    block_sync();                 // all waves' K_j,V_j resident; phase j-1 done
    if (j + 1 < nt) issue(j + 1); // K->slot (j+1)&1 (read done), V->(j+1)%3

    __builtin_amdgcn_s_setprio(1);
    if (j > 0) pv(j - 1);         // PV_{j-1}, one phase late (before rescale!)

    // S^T = K (Q*SCALE*log2e)^T from Ks[j&1]: s[j16][r] is
    // (k = j*32 + 16*j16 + 4*g + r, q = qrow + l15)
    const char* Kb = (const char*)(KsAll + (j & 1) * 2048);
    f32x4 s[2] = {};
#pragma unroll
    for (int j16 = 0; j16 < 2; ++j16) {
      const int r0 = j16 * 16 + l15;
      const char* rp = Kb + r0 * 128;
      const int sw = (r0 & 7) << 4;
      bf16x8 k0 = *(const bf16x8*)(rp + ((g * 16) ^ sw));
      bf16x8 k1 = *(const bf16x8*)(rp + ((64 + g * 16) ^ sw));
      s[j16] = __builtin_amdgcn_mfma_f32_16x16x32_bf16(k0, qf[0], s[j16], 0, 0, 0);
      s[j16] = __builtin_amdgcn_mfma_f32_16x16x32_bf16(k1, qf[1], s[j16], 0, 0, 0);
    }
    __builtin_amdgcn_s_setprio(0);

    // causal mask: k > q (tiles overlapping the diagonal; fully-masked tiles
    // for low waves fall out as all -1e30 -> exp2 = 0)
    const int kb = j * 32;
    if (kb + 31 > qrow) {
#pragma unroll
      for (int j16 = 0; j16 < 2; ++j16)
#pragma unroll
        for (int r = 0; r < 4; ++r)
          if (kb + j16 * 16 + g * 4 + r > qrow + l15) s[j16][r] = -1e30f;
    }

    // online softmax: cross-lane only in the (rare) rescale branch
    float pmax = fmaxf(fmaxf(fmaxf(s[0][0], s[0][1]), fmaxf(s[0][2], s[0][3])),
                       fmaxf(fmaxf(s[1][0], s[1][1]), fmaxf(s[1][2], s[1][3])));
    if (!__all(pmax <= m_s + 11.0f)) {
      float rm = fmaxf(pmax, __shfl_xor(pmax, 16));
      rm = fmaxf(rm, __shfl_xor(rm, 32));       // row-uniform max
      float mn = fmaxf(m_s, rm);
      float sc = fexp2(m_s - mn);
      m_s = mn;
      l_p *= sc;
#pragma unroll
      for (int c = 0; c < 4; ++c)
#pragma unroll
        for (int r = 0; r < 4; ++r) acc[c][r] *= sc;
    }

    float ps = 0.f;
#pragma unroll
    for (int j16 = 0; j16 < 2; ++j16)
#pragma unroll
      for (int r = 0; r < 4; ++r) {
        s[j16][r] = fexp2(s[j16][r] - m_s);
        ps += s[j16][r];
      }
    l_p += ps;                    // per-lane partial (reduced in epilogue)

    // P -> LDS [q][k], chunk-XOR swizzled; b64 per j16
#pragma unroll
    for (int j16 = 0; j16 < 2; ++j16) {
      bf16x4 pk;
      pk[0] = (bf16_t)s[j16][0]; pk[1] = (bf16_t)s[j16][1];
      pk[2] = (bf16_t)s[j16][2]; pk[3] = (bf16_t)s[j16][3];
      *(bf16x4*)&Plds[w][l15][(((2 * j16 + (g >> 1)) ^ (l15 & 3)) * 8) + (g & 1) * 4] = pk;
    }
  }

  // epilogue: PV for the last tile, then one quad l-reduce, then O^T write
  pv(nt - 1);

  float lt = l_p;
  lt += __shfl_xor(lt, 16);
  lt += __shfl_xor(lt, 32);
  const float inv = 1.0f / lt;
#pragma unroll
  for (int c = 0; c < 4; ++c) {
    bf16x4 o;
#pragma unroll
    for (int r = 0; r < 4; ++r) o[r] = (bf16_t)(acc[c][r] * inv);
    *(bf16x4*)&Oattn[(size_t)(qrow + l15) * E_DIM + h * 64 + c * 16 + g * 4] = o;
  }
}

extern "C" void kernel_launch(void* const* d_in, const int* in_sizes, int n_in,
                              void* d_out, int out_size, void* d_ws, size_t ws_size,
                              hipStream_t stream) {
  const float* q  = (const float*)d_in[0];
  const float* k  = (const float*)d_in[1];
  const float* v  = (const float*)d_in[2];
  const float* Wq = (const float*)d_in[3];
  const float* Wk = (const float*)d_in[4];
  const float* Wv = (const float*)d_in[5];
  const float* Wo = (const float*)d_in[6];
  float* out = (float*)d_out;

  const size_t TE = (size_t)T_DIM * E_DIM;   // 4M elems
  const size_t EE = (size_t)E_DIM * E_DIM;   // 1M elems
  dim3 blk(256);

  if (ws_size >= (size_t)56 * 1024 * 1024) {
    bf16_t* qb  = (bf16_t*)d_ws;          // reused as Oa after projections
    bf16_t* kb  = qb + TE;
    bf16_t* vb  = kb + TE;
    bf16_t* Wqb = vb + TE;
    bf16_t* Wkb = Wqb + EE;
    bf16_t* Wvb = Wkb + EE;
    bf16_t* Wob = Wvb + EE;
    bf16_t* Qp  = Wob + EE;
    bf16_t* Kp  = Qp + TE;
    bf16_t* Vt  = Kp + TE;                // [E][T]
    bf16_t* Oa  = qb;                     // alias

    cvt_all<<<2048, blk, 0, stream>>>(q, k, v, Wq, Wk, Wv, Wo,
                                      qb, kb, vb, Wqb, Wkb, Wvb, Wob);
    proj_qkv<<<dim3(768), blk, 0, stream>>>(qb, kb, vb, Wqb, Wkb, Wvb, Qp, Kp, Vt);
    attn_fwd<<<dim3(1024), blk, 0, stream>>>(Qp, Kp, Vt, Oa);
    gemm_fin<<<dim3(8, 64), blk, 0, stream>>>(Oa, Wob, out);
  } else {
    bf16_t* Qp = (bf16_t*)d_ws;
    bf16_t* Kp = Qp + TE;
    bf16_t* Vt = Kp + TE;
    bf16_t* Oa = Vt + TE;
    gemm_bt<float, float, bf16_t><<<dim3(8, 32), blk, 0, stream>>>(q, Wq, Qp, T_DIM, E_DIM, E_DIM, QSCALE_F);
    gemm_bt<float, float, bf16_t><<<dim3(8, 32), blk, 0, stream>>>(k, Wk, Kp, T_DIM, E_DIM, E_DIM, 1.0f);
    gemm_bt<float, float, bf16_t><<<dim3(32, 8), blk, 0, stream>>>(Wv, v, Vt, E_DIM, T_DIM, E_DIM, 1.0f);
    attn_fwd<<<dim3(1024), blk, 0, stream>>>(Qp, Kp, Vt, Oa);
    gemm_bt<bf16_t, float, float><<<dim3(8, 32), blk, 0, stream>>>(Oa, Wo, out, T_DIM, E_DIM, E_DIM, 1.0f);
  }
}

// Round 13
// 131.573 us; speedup vs baseline: 1.1507x; 1.1507x over previous
//
#include <hip/hip_runtime.h>
#include <hip/hip_bf16.h>

// Problem constants (B=1)
#define T_DIM 4096
#define E_DIM 1024
#define H_DIM 16
#define HD_DIM 64
#define LOG2E_F 1.4426950408889634f
#define QSCALE_F (0.125f * LOG2E_F)   // SCALE * log2(e), folded into Qp

typedef __bf16 bf16_t;
typedef __bf16 bf16x8 __attribute__((ext_vector_type(8)));
typedef __bf16 bf16x4 __attribute__((ext_vector_type(4)));
typedef float  f32x4  __attribute__((ext_vector_type(4)));

// ---- helpers ----
__device__ inline void stage8(bf16_t* dst, const float* src) {
  const f32x4* s4 = (const f32x4*)src;
  f32x4 a = s4[0], b = s4[1];
  bf16x8 o;
  o[0] = (bf16_t)a[0]; o[1] = (bf16_t)a[1]; o[2] = (bf16_t)a[2]; o[3] = (bf16_t)a[3];
  o[4] = (bf16_t)b[0]; o[5] = (bf16_t)b[1]; o[6] = (bf16_t)b[2]; o[7] = (bf16_t)b[3];
  *(bf16x8*)dst = o;
}
__device__ inline void stage8(bf16_t* dst, const bf16_t* src) {
  *(bf16x8*)dst = *(const bf16x8*)src;
}

__device__ inline void gld_lds16(const bf16_t* g, bf16_t* l) {
  __builtin_amdgcn_global_load_lds(
      (const __attribute__((address_space(1))) unsigned int*)g,
      (__attribute__((address_space(3))) unsigned int*)l, 16, 0, 0);
}

__device__ inline float fexp2(float x) {  // raw v_exp_f32 (exp2)
  float r;
  asm("v_exp_f32 %0, %1" : "=v"(r) : "v"(x));
  return r;
}

// raw barrier (no implicit vmcnt(0) drain) + compiler memory fence
__device__ inline void block_sync() {
  asm volatile("" ::: "memory");
  __builtin_amdgcn_s_barrier();
  asm volatile("" ::: "memory");
}

// ---- fp32 -> bf16 conversion for all 7 inputs (one launch) ----
__global__ __launch_bounds__(256) void cvt_all(
    const float* __restrict__ q, const float* __restrict__ k, const float* __restrict__ v,
    const float* __restrict__ Wq, const float* __restrict__ Wk,
    const float* __restrict__ Wv, const float* __restrict__ Wo,
    bf16_t* qb, bf16_t* kb, bf16_t* vb,
    bf16_t* Wqb, bf16_t* Wkb, bf16_t* Wvb, bf16_t* Wob) {
  for (int u = blockIdx.x * 256 + threadIdx.x; u < 2097152; u += gridDim.x * 256) {
    const float* s; bf16_t* d; int i;
    if (u < 1572864) {
      int seg = u >> 19, off = u & 524287;
      s = seg == 0 ? q : (seg == 1 ? k : v);
      d = seg == 0 ? qb : (seg == 1 ? kb : vb);
      i = off;
    } else {
      int w = u - 1572864;
      int seg = w >> 17, off = w & 131071;
      s = seg == 0 ? Wq : seg == 1 ? Wk : seg == 2 ? Wv : Wo;
      d = seg == 0 ? Wqb : seg == 1 ? Wkb : seg == 2 ? Wvb : Wob;
      i = off;
    }
    stage8(d + (size_t)i * 8, s + (size_t)i * 8);
  }
}

// ---- bf16 GEMM tile body (m97 structure): C = (A[M][1024] x B[N][1024]^T)*cs
template <int MF, int NF, typename TC>
__device__ __forceinline__ void gemm_body(const bf16_t* __restrict__ A,
                                          const bf16_t* __restrict__ B,
                                          TC* __restrict__ C,
                                          int ldC, int bm, int bn, float cs) {
  constexpr int BM = 32 * MF, BN = 32 * NF;
  __shared__ alignas(16) bf16_t As[BM][64];
  __shared__ alignas(16) bf16_t Bs[BN][64];
  const int tid  = threadIdx.x;
  const int lane = tid & 63, w = tid >> 6;
  const int g = lane >> 4, l15 = lane & 15;
  const int wr = w >> 1, wc = w & 1;

  f32x4 acc[MF][NF] = {};

  for (int kt = 0; kt < 1024; kt += 64) {
    if (kt) __syncthreads();
#pragma unroll
    for (int p = 0; p < MF; ++p) {
      int s = p * 256 + tid;
      int row = s >> 3, c = s & 7;
      int cg = c ^ (row & 7);
      gld_lds16(&A[(size_t)(bm + row) * 1024 + kt + cg * 8], &As[0][0] + s * 8);
    }
#pragma unroll
    for (int p = 0; p < NF; ++p) {
      int s = p * 256 + tid;
      int row = s >> 3, c = s & 7;
      int cg = c ^ (row & 7);
      gld_lds16(&B[(size_t)(bn + row) * 1024 + kt + cg * 8], &Bs[0][0] + s * 8);
    }
    asm volatile("s_waitcnt vmcnt(0)" ::: "memory");
    __syncthreads();

#pragma unroll
    for (int hh = 0; hh < 2; ++hh) {
      bf16x8 af[MF], bfr[NF];
#pragma unroll
      for (int m = 0; m < MF; ++m) {
        int row = wr * (16 * MF) + m * 16 + l15;
        af[m] = *(const bf16x8*)(&As[0][0] + row * 64 + (((hh * 4 + g) ^ (row & 7)) * 8));
      }
#pragma unroll
      for (int n = 0; n < NF; ++n) {
        int row = wc * (16 * NF) + n * 16 + l15;
        bfr[n] = *(const bf16x8*)(&Bs[0][0] + row * 64 + (((hh * 4 + g) ^ (row & 7)) * 8));
      }
#pragma unroll
      for (int m = 0; m < MF; ++m)
#pragma unroll
        for (int n = 0; n < NF; ++n)
          acc[m][n] = __builtin_amdgcn_mfma_f32_16x16x32_bf16(af[m], bfr[n], acc[m][n], 0, 0, 0);
    }
  }

#pragma unroll
  for (int m = 0; m < MF; ++m)
#pragma unroll
    for (int n = 0; n < NF; ++n)
#pragma unroll
      for (int r = 0; r < 4; ++r) {
        int row = bm + wr * (16 * MF) + m * 16 + g * 4 + r;
        int col = bn + wc * (16 * NF) + n * 16 + l15;
        C[(size_t)row * ldC + col] = (TC)(acc[m][n][r] * cs);
      }
}

// ---- fused Q/K/V projections: one launch, 768 blocks (3 blocks/CU) ----
__global__ __launch_bounds__(256) void proj_qkv(
    const bf16_t* __restrict__ qb, const bf16_t* __restrict__ kb,
    const bf16_t* __restrict__ vb,
    const bf16_t* __restrict__ Wqb, const bf16_t* __restrict__ Wkb,
    const bf16_t* __restrict__ Wvb,
    bf16_t* Qp, bf16_t* Kp, bf16_t* Vt) {
  const int bid = blockIdx.x;
  const int which = bid >> 8, t = bid & 255;
  const bf16_t *A, *B; bf16_t* C; int ldC, bm, bn; float cs;
  if (which == 0) {
    A = qb;  B = Wqb; C = Qp; ldC = 1024;
    bm = (t >> 3) * 128; bn = (t & 7) * 128; cs = QSCALE_F;
  } else if (which == 1) {
    A = kb;  B = Wkb; C = Kp; ldC = 1024;
    bm = (t >> 3) * 128; bn = (t & 7) * 128; cs = 1.0f;
  } else {
    A = Wvb; B = vb;  C = Vt; ldC = 4096;
    bm = (t >> 5) * 128; bn = (t & 31) * 128; cs = 1.0f;
  }
  gemm_body<4, 4, bf16_t>(A, B, C, ldC, bm, bn, cs);
}

// ---- final GEMM: out = Oa @ Wo^T, 64x128 tiles (grid 8x64, 2 blocks/CU) ----
__global__ __launch_bounds__(256) void gemm_fin(const bf16_t* __restrict__ A,
                                                const bf16_t* __restrict__ B,
                                                float* __restrict__ C) {
  gemm_body<2, 4, float>(A, B, C, 1024, blockIdx.y * 64, blockIdx.x * 128, 1.0f);
}

// ---- fallback GEMM (fp32 staging, used only if ws too small) ----
template <typename TA, typename TB, typename TC>
__global__ __launch_bounds__(256) void gemm_bt(const TA* __restrict__ A,
                                               const TB* __restrict__ B,
                                               TC* __restrict__ C,
                                               int M, int N, int K, float cscale) {
  __shared__ alignas(16) bf16_t As[128][40];
  __shared__ alignas(16) bf16_t Bs[128][40];
  const int tid  = threadIdx.x;
  const int lane = tid & 63, w = tid >> 6;
  const int g = lane >> 4, l15 = lane & 15;
  const int wr = w >> 1, wc = w & 1;
  const int bm = blockIdx.y * 128, bn = blockIdx.x * 128;

  f32x4 acc[4][4] = {};

  for (int kt = 0; kt < K; kt += 32) {
    __syncthreads();
#pragma unroll
    for (int i = 0; i < 2; ++i) {
      int vv  = tid + i * 256;
      int row = vv >> 2, c8 = (vv & 3) * 8;
      stage8(&As[row][c8], &A[(size_t)(bm + row) * K + kt + c8]);
      stage8(&Bs[row][c8], &B[(size_t)(bn + row) * K + kt + c8]);
    }
    __syncthreads();

    bf16x8 af[4], bfr[4];
#pragma unroll
    for (int m = 0; m < 4; ++m)
      af[m] = *(const bf16x8*)&As[wr * 64 + m * 16 + l15][g * 8];
#pragma unroll
    for (int n = 0; n < 4; ++n)
      bfr[n] = *(const bf16x8*)&Bs[wc * 64 + n * 16 + l15][g * 8];
#pragma unroll
    for (int m = 0; m < 4; ++m)
#pragma unroll
      for (int n = 0; n < 4; ++n)
        acc[m][n] = __builtin_amdgcn_mfma_f32_16x16x32_bf16(af[m], bfr[n], acc[m][n], 0, 0, 0);
  }

#pragma unroll
  for (int m = 0; m < 4; ++m)
#pragma unroll
    for (int n = 0; n < 4; ++n)
#pragma unroll
      for (int r = 0; r < 4; ++r) {
        int row = bm + wr * 64 + m * 16 + g * 4 + r;
        int col = bn + wc * 64 + n * 16 + l15;
        C[(size_t)row * N + col] = (TC)(acc[m][n][r] * cscale);
      }
}

// ---- Flash attention, causal, online softmax (log2 domain, pre-scaled Q) ----
// KVBLK=64 (round-11 structure), QBLK=64, 4 waves (256 thr).
// PERFECT BALANCE: 512 blocks, each processes TWO Q-tiles sequentially --
// qi = 63-i then qi = i -- so every block does exactly 65 KV-tile phases.
// All 512 co-resident (2/CU at 49 KB LDS), equal cost, zero tail (round-12
// lesson: occupancy was grid/balance-bound, not LDS-bound).
// Swapped-operand QK^T: lane l holds q = qrow+l15, k-band {16*j16+4g+r};
// m quad-reduced only in the rare rescale branch; l kept per-lane partial,
// one quad-reduce per pass in the epilogue.
__global__ __launch_bounds__(256) void attn_fwd(const bf16_t* __restrict__ Qp,
                                                const bf16_t* __restrict__ Kp,
                                                const bf16_t* __restrict__ Vt,
                                                bf16_t* __restrict__ Oattn) {
  const int bid = blockIdx.x;          // 0..511
  const int h  = bid & 15;             // xcd = bid%8 = h%8: 2 heads per XCD L2
  const int ii = bid >> 4;             // 0..31
  const int tid = threadIdx.x, lane = tid & 63, w = tid >> 6;
  const int g = lane >> 4, l15 = lane & 15;

  __shared__ alignas(16) bf16_t Ks[2][64][64];   // 16 KB, swizzled
  __shared__ alignas(16) bf16_t Vs[3][64][64];   // 24 KB, swizzled
  __shared__ alignas(16) bf16_t Plds[4][16][72]; // 9 KB, [q][k], 144B stride

  // staging: 256 threads x 2 chunks x 16B per K and per V tile (64x64 bf16).
  // Pass-invariant (same head for both passes).
  const int row0 = tid >> 3, c0 = tid & 7;
  const int cgo = (c0 ^ (row0 & 7)) * 8;           // source-side swizzle
  const bf16_t* srcK0 = Kp + (size_t)row0 * E_DIM + h * 64 + cgo;
  const bf16_t* srcK1 = srcK0 + (size_t)32 * E_DIM;       // (row+32)&7 == row&7
  const bf16_t* srcV0 = Vt + (size_t)(h * 64 + row0) * T_DIM + cgo;
  const bf16_t* srcV1 = srcV0 + (size_t)32 * T_DIM;
  bf16_t* KsAll = &Ks[0][0][0];
  bf16_t* VsAll = &Vs[0][0][0];
  const size_t KADV = (size_t)64 * E_DIM;

  auto issue = [&](int t) {
    bf16_t* kd = KsAll + (t & 1) * 4096;
    bf16_t* vd = VsAll + (t % 3) * 4096;
    gld_lds16(srcK0 + (size_t)t * KADV, kd + tid * 8);
    gld_lds16(srcK1 + (size_t)t * KADV, kd + (256 + tid) * 8);
    gld_lds16(srcV0 + (size_t)t * 64,   vd + tid * 8);
    gld_lds16(srcV1 + (size_t)t * 64,   vd + (256 + tid) * 8);
  };

  f32x4 acc[4];               // acc[c][r]: O^T[d = c*16 + g*4 + r][q = l15]
  float m_s, l_p;             // m row-uniform; l per-lane partial

  auto pv = [&](int t) {
    const char* Vb = (const char*)(VsAll + (t % 3) * 4096);
    bf16x8 pf0 = *(const bf16x8*)&Plds[w][l15][g * 8];        // k = g*8..+7
    bf16x8 pf1 = *(const bf16x8*)&Plds[w][l15][32 + g * 8];   // k = 32+g*8..
#pragma unroll
    for (int c = 0; c < 4; ++c) {
      const int vr = c * 16 + l15;
      const char* rp = Vb + vr * 128;
      const int sw = (vr & 7) << 4;
      bf16x8 v0 = *(const bf16x8*)(rp + ((g * 16) ^ sw));
      bf16x8 v1 = *(const bf16x8*)(rp + ((64 + g * 16) ^ sw));
      acc[c] = __builtin_amdgcn_mfma_f32_16x16x32_bf16(v0, pf0, acc[c], 0, 0, 0);
      acc[c] = __builtin_amdgcn_mfma_f32_16x16x32_bf16(v1, pf1, acc[c], 0, 0, 0);
    }
  };

  for (int pass = 0; pass < 2; ++pass) {
    const int qi = pass ? ii : 63 - ii;          // 65 phases total per block
    const int qrow = qi * 64 + w * 16;
    const int nt = qi + 1;

    bf16x8 qf[2];
    {
      const bf16_t* qp = &Qp[(size_t)(qrow + l15) * E_DIM + h * 64 + g * 8];
      qf[0] = *(const bf16x8*)qp;
      qf[1] = *(const bf16x8*)(qp + 32);
    }
#pragma unroll
    for (int c = 0; c < 4; ++c)
#pragma unroll
      for (int r = 0; r < 4; ++r) acc[c][r] = 0.f;
    m_s = -1e30f; l_p = 0.f;

    if (pass) block_sync();   // previous pass's last reads of Ks/Vs complete
    issue(0);

    for (int j = 0; j < nt; ++j) {
      asm volatile("s_waitcnt vmcnt(0)" ::: "memory");
      block_sync();               // all waves' K_j,V_j resident; phase j-1 done
      if (j + 1 < nt) issue(j + 1);

      __builtin_amdgcn_s_setprio(1);
      if (j > 0) pv(j - 1);       // PV_{j-1}, one phase late (before rescale!)

      // S^T = K (Q*SCALE*log2e)^T from Ks[j&1]: s[j16][r] is
      // (k = j*64 + 16*j16 + 4*g + r, q = qrow + l15)
      const char* Kb = (const char*)(KsAll + (j & 1) * 4096);
      f32x4 s[4] = {};
#pragma unroll
      for (int j16 = 0; j16 < 4; ++j16) {
        const int r0 = j16 * 16 + l15;
        const char* rp = Kb + r0 * 128;
        const int sw = (r0 & 7) << 4;
        bf16x8 k0 = *(const bf16x8*)(rp + ((g * 16) ^ sw));
        bf16x8 k1 = *(const bf16x8*)(rp + ((64 + g * 16) ^ sw));
        s[j16] = __builtin_amdgcn_mfma_f32_16x16x32_bf16(k0, qf[0], s[j16], 0, 0, 0);
        s[j16] = __builtin_amdgcn_mfma_f32_16x16x32_bf16(k1, qf[1], s[j16], 0, 0, 0);
      }
      __builtin_amdgcn_s_setprio(0);

      // causal mask, diagonal tile only: k > q
      if (j == nt - 1) {
        const int kb = j * 64;
#pragma unroll
        for (int j16 = 0; j16 < 4; ++j16)
#pragma unroll
          for (int r = 0; r < 4; ++r)
            if (kb + j16 * 16 + g * 4 + r > qrow + l15) s[j16][r] = -1e30f;
      }

      // online softmax: cross-lane only in the (rare) rescale branch.
      // per-lane pmax <= m_s+11 for ALL lanes implies row max <= m_s+11.
      float pmax = s[0][0];
#pragma unroll
      for (int j16 = 0; j16 < 4; ++j16)
#pragma unroll
        for (int r = 0; r < 4; ++r) pmax = fmaxf(pmax, s[j16][r]);

      if (!__all(pmax <= m_s + 11.0f)) {
        float rm = fmaxf(pmax, __shfl_xor(pmax, 16));
        rm = fmaxf(rm, __shfl_xor(rm, 32));     // row-uniform max
        float mn = fmaxf(m_s, rm);
        float sc = fexp2(m_s - mn);
        m_s = mn;
        l_p *= sc;
#pragma unroll
        for (int c = 0; c < 4; ++c)
#pragma unroll
          for (int r = 0; r < 4; ++r) acc[c][r] *= sc;
      }

      float ps = 0.f;
#pragma unroll
      for (int j16 = 0; j16 < 4; ++j16)
#pragma unroll
        for (int r = 0; r < 4; ++r) {
          s[j16][r] = fexp2(s[j16][r] - m_s);
          ps += s[j16][r];
        }
      l_p += ps;                  // per-lane partial (reduced in epilogue)

      // P -> LDS [q][k]: per j16 the 4 r-values are k-consecutive -> b64
#pragma unroll
      for (int j16 = 0; j16 < 4; ++j16) {
        bf16x4 pk;
        pk[0] = (bf16_t)s[j16][0]; pk[1] = (bf16_t)s[j16][1];
        pk[2] = (bf16_t)s[j16][2]; pk[3] = (bf16_t)s[j16][3];
        *(bf16x4*)&Plds[w][l15][j16 * 16 + g * 4] = pk;
      }
    }

    // epilogue: PV for the last tile, one quad l-reduce, O^T write
    pv(nt - 1);

    float lt = l_p;
    lt += __shfl_xor(lt, 16);
    lt += __shfl_xor(lt, 32);
    const float inv = 1.0f / lt;
#pragma unroll
    for (int c = 0; c < 4; ++c) {
      bf16x4 o;
#pragma unroll
      for (int r = 0; r < 4; ++r) o[r] = (bf16_t)(acc[c][r] * inv);
      *(bf16x4*)&Oattn[(size_t)(qrow + l15) * E_DIM + h * 64 + c * 16 + g * 4] = o;
    }
  }
}

extern "C" void kernel_launch(void* const* d_in, const int* in_sizes, int n_in,
                              void* d_out, int out_size, void* d_ws, size_t ws_size,
                              hipStream_t stream) {
  const float* q  = (const float*)d_in[0];
  const float* k  = (const float*)d_in[1];
  const float* v  = (const float*)d_in[2];
  const float* Wq = (const float*)d_in[3];
  const float* Wk = (const float*)d_in[4];
  const float* Wv = (const float*)d_in[5];
  const float* Wo = (const float*)d_in[6];
  float* out = (float*)d_out;

  const size_t TE = (size_t)T_DIM * E_DIM;   // 4M elems
  const size_t EE = (size_t)E_DIM * E_DIM;   // 1M elems
  dim3 blk(256);

  if (ws_size >= (size_t)56 * 1024 * 1024) {
    bf16_t* qb  = (bf16_t*)d_ws;          // reused as Oa after projections
    bf16_t* kb  = qb + TE;
    bf16_t* vb  = kb + TE;
    bf16_t* Wqb = vb + TE;
    bf16_t* Wkb = Wqb + EE;
    bf16_t* Wvb = Wkb + EE;
    bf16_t* Wob = Wvb + EE;
    bf16_t* Qp  = Wob + EE;
    bf16_t* Kp  = Qp + TE;
    bf16_t* Vt  = Kp + TE;                // [E][T]
    bf16_t* Oa  = qb;                     // alias

    cvt_all<<<2048, blk, 0, stream>>>(q, k, v, Wq, Wk, Wv, Wo,
                                      qb, kb, vb, Wqb, Wkb, Wvb, Wob);
    proj_qkv<<<dim3(768), blk, 0, stream>>>(qb, kb, vb, Wqb, Wkb, Wvb, Qp, Kp, Vt);
    attn_fwd<<<dim3(512), blk, 0, stream>>>(Qp, Kp, Vt, Oa);
    gemm_fin<<<dim3(8, 64), blk, 0, stream>>>(Oa, Wob, out);
  } else {
    bf16_t* Qp = (bf16_t*)d_ws;
    bf16_t* Kp = Qp + TE;
    bf16_t* Vt = Kp + TE;
    bf16_t* Oa = Vt + TE;
    gemm_bt<float, float, bf16_t><<<dim3(8, 32), blk, 0, stream>>>(q, Wq, Qp, T_DIM, E_DIM, E_DIM, QSCALE_F);
    gemm_bt<float, float, bf16_t><<<dim3(8, 32), blk, 0, stream>>>(k, Wk, Kp, T_DIM, E_DIM, E_DIM, 1.0f);
    gemm_bt<float, float, bf16_t><<<dim3(32, 8), blk, 0, stream>>>(Wv, v, Vt, E_DIM, T_DIM, E_DIM, 1.0f);
    attn_fwd<<<dim3(512), blk, 0, stream>>>(Qp, Kp, Vt, Oa);
    gemm_bt<bf16_t, float, float><<<dim3(8, 32), blk, 0, stream>>>(Oa, Wo, out, T_DIM, E_DIM, E_DIM, 1.0f);
  }
}